// Round 4
// baseline (500.540 us; speedup 1.0000x reference)
//
#include <hip/hip_runtime.h>

#define SCAN_B 1024

using bf16x8 = __attribute__((ext_vector_type(8))) short;
using f32x4  = __attribute__((ext_vector_type(4))) float;
typedef unsigned short ushort4v __attribute__((ext_vector_type(4)));

// split fp32 into bf16 hi (truncation) + bf16 lo (RNE of exact remainder)
__device__ inline void split1(float x, unsigned short& h, unsigned short& l) {
  unsigned u  = __float_as_uint(x);
  unsigned hu = u & 0xFFFF0000u;
  float lo = x - __uint_as_float(hu);
  unsigned lu = __float_as_uint(lo);
  h = (unsigned short)(hu >> 16);
  l = (unsigned short)((lu + 0x7FFFu + ((lu >> 16) & 1u)) >> 16);
}

// ---------------- precompute kernels ----------------

__global__ void zero2_kernel(int* __restrict__ a, int* __restrict__ b, int n) {
  int i = blockIdx.x * blockDim.x + threadIdx.x;
  if (i < n) { a[i] = 0; b[i] = 0; }
}

__global__ void count_kernel(const int* __restrict__ ei, int* __restrict__ cnt, int E) {
  int i = blockIdx.x * blockDim.x + threadIdx.x;
  if (i < E) atomicAdd(&cnt[ei[E + i]], 1);
}

__global__ void dinv_kernel(const int* __restrict__ cnt, float* __restrict__ dinv, int n) {
  int i = blockIdx.x * blockDim.x + threadIdx.x;
  if (i < n) dinv[i] = rsqrtf((float)(cnt[i] + 1));
}

// scan over (cnt[i] + 1): row length includes the appended self edge
__global__ void scan1_kernel(const int* __restrict__ cnt, int* __restrict__ rowstart,
                             int* __restrict__ bsum, int n) {
  __shared__ int sm[SCAN_B];
  const int t = threadIdx.x;
  const int i = blockIdx.x * SCAN_B + t;
  int v = (i < n) ? (cnt[i] + 1) : 0;
  sm[t] = v;
  __syncthreads();
  for (int off = 1; off < SCAN_B; off <<= 1) {
    int x = (t >= off) ? sm[t - off] : 0;
    __syncthreads();
    if (t >= off) sm[t] += x;
    __syncthreads();
  }
  if (i < n) rowstart[i] = sm[t] - v;
  if (t == SCAN_B - 1) bsum[blockIdx.x] = sm[t];
}

__global__ void scan2_kernel(int* __restrict__ bsum, int nb) {
  __shared__ int sm[SCAN_B];
  const int t = threadIdx.x;
  int v = (t < nb) ? bsum[t] : 0;
  sm[t] = v;
  __syncthreads();
  for (int off = 1; off < SCAN_B; off <<= 1) {
    int x = (t >= off) ? sm[t - off] : 0;
    __syncthreads();
    if (t >= off) sm[t] += x;
    __syncthreads();
  }
  if (t < nb) bsum[t] = sm[t] - v;
}

__global__ void scan3_kernel(int* __restrict__ rowstart, const int* __restrict__ bsum, int n) {
  int i = blockIdx.x * blockDim.x + threadIdx.x;
  if (i < n) rowstart[i] += bsum[i / SCAN_B];
}

__global__ void fill_kernel(const int* __restrict__ ei, int* __restrict__ fillc,
                            const int* __restrict__ rowstart, const float* __restrict__ dinv,
                            float2* __restrict__ ew, int E) {
  int e = blockIdx.x * blockDim.x + threadIdx.x;
  if (e < E) {
    int s = ei[e];
    int d = ei[E + e];
    int p = atomicAdd(&fillc[d], 1);
    ew[rowstart[d] + p] = make_float2(__int_as_float(s), dinv[s] * dinv[d]);
  }
}

// self edge goes in the last slot of each row: weight dinv^2
__global__ void selfedge_kernel(const int* __restrict__ rowstart, const int* __restrict__ cnt,
                                const float* __restrict__ dinv, float2* __restrict__ ew, int N) {
  int n = blockIdx.x * blockDim.x + threadIdx.x;
  if (n < N) {
    float dn = dinv[n];
    ew[rowstart[n] + cnt[n]] = make_float2(__int_as_float(n), dn * dn);
  }
}

// W [K][N] fp32 -> transposed split Wh/Wl [N][K] bf16 (k-contiguous for MFMA staging)
__global__ void wsplit_kernel(const float* __restrict__ W, unsigned short* __restrict__ Wh,
                              unsigned short* __restrict__ Wl, int K, int N) {
  int i = blockIdx.x * blockDim.x + threadIdx.x;
  if (i < K * N) {
    int k = i / N, n = i % N;
    unsigned short h, l;
    split1(W[i], h, l);
    Wh[(size_t)n * K + k] = h;
    Wl[(size_t)n * K + k] = l;
  }
}

// ---------------- split-bf16 MFMA GEMM, reg-staged with load/MFMA overlap ----------------
// C[M x N] = A[M x K] @ B[K x N], BN == N. A fp32 (split in-kernel),
// B pre-split/transposed: Wh/Wl [N][K] bf16. BK=32, 256 threads = 4 waves (2x2).
// acc = Ah*Bh + Ah*Bl + Al*Bh

template <int BM, int BN>
__global__ void __launch_bounds__(256)
gemm_mfma_kernel(const float* __restrict__ A, const unsigned short* __restrict__ Wh,
                 const unsigned short* __restrict__ Wl, float* __restrict__ C,
                 int M, int K) {
  constexpr int BK   = 32;
  constexpr int LDK  = 40;              // bf16 elems per LDS row (80B)
  constexpr int MR   = BM / 2 / 16;     // 4
  constexpr int NR   = BN / 2 / 16;     // 4 or 2
  constexpr int N    = BN;
  constexpr int BCOP = (BN * 4) / 256;  // B copy iters (2 for BN=128, 1 for BN=64)

  __shared__ __align__(16) unsigned short Ah[BM][LDK];
  __shared__ __align__(16) unsigned short Al[BM][LDK];
  __shared__ __align__(16) unsigned short Bh[BN][LDK];
  __shared__ __align__(16) unsigned short Bl[BN][LDK];

  const int tid  = threadIdx.x;
  const int lane = tid & 63;
  const int w    = tid >> 6;
  const int wm   = w >> 1;
  const int wn   = w & 1;
  const int fr   = lane & 15;
  const int fq   = lane >> 4;
  const int m0   = blockIdx.x * BM;

  const int a_c = tid & 7;
  const int a_m = tid >> 3;

  float4 av[4];
  uint4  bhv[BCOP], blv[BCOP];

  auto loadA = [&](int kt) {
#pragma unroll
    for (int p = 0; p < 4; ++p) {
      const int gm = m0 + a_m + 32 * p;
      av[p] = (gm < M) ? *(const float4*)&A[(size_t)gm * K + kt + 4 * a_c]
                       : make_float4(0.f, 0.f, 0.f, 0.f);
    }
  };
  auto loadB = [&](int kt) {
#pragma unroll
    for (int i = 0; i < BCOP; ++i) {
      const int idx = tid + i * 256;
      const int r = idx >> 2, jj = idx & 3;
      bhv[i] = *(const uint4*)&Wh[(size_t)r * K + kt + 8 * jj];
      blv[i] = *(const uint4*)&Wl[(size_t)r * K + kt + 8 * jj];
    }
  };

  f32x4 acc[MR][NR] = {};

  loadA(0);
  loadB(0);

  for (int kt = 0; kt < K; kt += BK) {
    __syncthreads();   // previous tile's LDS reads complete

    // ---- regs -> LDS (A split + B copy) ----
#pragma unroll
    for (int p = 0; p < 4; ++p) {
      const int r = a_m + 32 * p;
      ushort4v hv, lv;
      split1(av[p].x, ((unsigned short*)&hv)[0], ((unsigned short*)&lv)[0]);
      split1(av[p].y, ((unsigned short*)&hv)[1], ((unsigned short*)&lv)[1]);
      split1(av[p].z, ((unsigned short*)&hv)[2], ((unsigned short*)&lv)[2]);
      split1(av[p].w, ((unsigned short*)&hv)[3], ((unsigned short*)&lv)[3]);
      *(ushort4v*)((char*)&Ah[0][0] + r * (LDK * 2) + a_c * 8) = hv;
      *(ushort4v*)((char*)&Al[0][0] + r * (LDK * 2) + a_c * 8) = lv;
    }
#pragma unroll
    for (int i = 0; i < BCOP; ++i) {
      const int idx = tid + i * 256;
      const int r = idx >> 2, jj = idx & 3;
      *(uint4*)((char*)&Bh[0][0] + r * (LDK * 2) + 16 * jj) = bhv[i];
      *(uint4*)((char*)&Bl[0][0] + r * (LDK * 2) + 16 * jj) = blv[i];
    }
    __syncthreads();

    // ---- issue next tile's global loads; they fly under the MFMAs ----
    if (kt + BK < K) {
      loadA(kt + BK);
      loadB(kt + BK);
    }

    // ---- fragments + MFMA ----
    bf16x8 ah[MR], al[MR], bh[NR], bl[NR];
#pragma unroll
    for (int mi = 0; mi < MR; ++mi) {
      const char* p = (const char*)&Ah[0][0] + (wm * MR * 16 + mi * 16 + fr) * (LDK * 2) + fq * 16;
      const char* q = (const char*)&Al[0][0] + (wm * MR * 16 + mi * 16 + fr) * (LDK * 2) + fq * 16;
      ah[mi] = *(const bf16x8*)p;
      al[mi] = *(const bf16x8*)q;
    }
#pragma unroll
    for (int ni = 0; ni < NR; ++ni) {
      const char* p = (const char*)&Bh[0][0] + (wn * NR * 16 + ni * 16 + fr) * (LDK * 2) + fq * 16;
      const char* q = (const char*)&Bl[0][0] + (wn * NR * 16 + ni * 16 + fr) * (LDK * 2) + fq * 16;
      bh[ni] = *(const bf16x8*)p;
      bl[ni] = *(const bf16x8*)q;
    }
#pragma unroll
    for (int mi = 0; mi < MR; ++mi)
#pragma unroll
      for (int ni = 0; ni < NR; ++ni) {
        acc[mi][ni] = __builtin_amdgcn_mfma_f32_16x16x32_bf16(ah[mi], bh[ni], acc[mi][ni], 0, 0, 0);
        acc[mi][ni] = __builtin_amdgcn_mfma_f32_16x16x32_bf16(ah[mi], bl[ni], acc[mi][ni], 0, 0, 0);
        acc[mi][ni] = __builtin_amdgcn_mfma_f32_16x16x32_bf16(al[mi], bh[ni], acc[mi][ni], 0, 0, 0);
      }
  }

  // ---- store: C/D map col=lane&15, row=(lane>>4)*4+reg ----
#pragma unroll
  for (int mi = 0; mi < MR; ++mi) {
    const int rbase = m0 + wm * MR * 16 + mi * 16 + fq * 4;
#pragma unroll
    for (int ni = 0; ni < NR; ++ni) {
      const int col = wn * NR * 16 + ni * 16 + fr;
#pragma unroll
      for (int r = 0; r < 4; ++r) {
        const int gm = rbase + r;
        if (gm < M) C[(size_t)gm * N + col] = acc[mi][ni][r];
      }
    }
  }
}

// ---------------- CSR pull aggregation: float4/lane, multi-edge per wave ----------------
// F=128: 32 lanes/edge, 2 edge slots; F=64: 16 lanes/edge, 4 edge slots. Unroll x2.
// Self loop is a regular CSR entry (last slot of each row).

template <int F>
__global__ void agg_kernel(const float* __restrict__ hin, const int* __restrict__ rowstart,
                           const int* __restrict__ cnt, const float2* __restrict__ ew,
                           const float* __restrict__ bias, float* __restrict__ outp, int N) {
  constexpr int LPE = F / 4;    // lanes per edge (float4 each)
  constexpr int EPW = 64 / LPE; // edge slots per wave
  const int wave = (int)((blockIdx.x * (size_t)blockDim.x + threadIdx.x) >> 6);
  if (wave >= N) return;
  const int lane = threadIdx.x & 63;
  const int sub  = lane / LPE;
  const int c    = lane % LPE;
  const int n    = wave;

  const int beg = rowstart[n];
  const int end = beg + cnt[n] + 1;   // incl. self edge

  float ax = 0.f, ay = 0.f, az = 0.f, aw = 0.f;
  int j = beg + sub;
  for (; j + EPW < end; j += 2 * EPW) {
    const float2 e0 = ew[j];
    const float2 e1 = ew[j + EPW];
    const float4 v0 = *(const float4*)&hin[(size_t)__float_as_int(e0.x) * F + c * 4];
    const float4 v1 = *(const float4*)&hin[(size_t)__float_as_int(e1.x) * F + c * 4];
    ax = fmaf(v0.x, e0.y, ax); ay = fmaf(v0.y, e0.y, ay);
    az = fmaf(v0.z, e0.y, az); aw = fmaf(v0.w, e0.y, aw);
    ax = fmaf(v1.x, e1.y, ax); ay = fmaf(v1.y, e1.y, ay);
    az = fmaf(v1.z, e1.y, az); aw = fmaf(v1.w, e1.y, aw);
  }
  if (j < end) {
    const float2 e = ew[j];
    const float4 v = *(const float4*)&hin[(size_t)__float_as_int(e.x) * F + c * 4];
    ax = fmaf(v.x, e.y, ax); ay = fmaf(v.y, e.y, ay);
    az = fmaf(v.z, e.y, az); aw = fmaf(v.w, e.y, aw);
  }

  // reduce across edge slots
#pragma unroll
  for (int d = LPE; d < 64; d <<= 1) {
    ax += __shfl_xor(ax, d);
    ay += __shfl_xor(ay, d);
    az += __shfl_xor(az, d);
    aw += __shfl_xor(aw, d);
  }

  if (lane < LPE) {
    const float4 bb = *(const float4*)&bias[c * 4];
    float4 r;
    r.x = fmaxf(ax + bb.x, 0.f);
    r.y = fmaxf(ay + bb.y, 0.f);
    r.z = fmaxf(az + bb.z, 0.f);
    r.w = fmaxf(aw + bb.w, 0.f);
    *(float4*)&outp[(size_t)n * F + c * 4] = r;
  }
}

// ---------------- launch ----------------

extern "C" void kernel_launch(void* const* d_in, const int* in_sizes, int n_in,
                              void* d_out, int out_size, void* d_ws, size_t ws_size,
                              hipStream_t stream) {
  const float* x  = (const float*)d_in[0];
  const int*   ei = (const int*)d_in[1];
  const float* W1 = (const float*)d_in[2];
  const float* b1 = (const float*)d_in[3];
  const float* W2 = (const float*)d_in[4];
  const float* b2 = (const float*)d_in[5];
  float* out = (float*)d_out;

  const int F1 = in_sizes[3];           // 128
  const int F2 = in_sizes[5];           // 64
  const int F0 = in_sizes[2] / F1;      // 512
  const int N  = in_sizes[0] / F0;      // 100000
  const int E  = in_sizes[1] / 2;       // 1600000

  char* ws = (char*)d_ws;
  size_t off = 0;
  auto alloc = [&](size_t bytes) -> void* {
    void* p = ws + off;
    off = (off + bytes + 255) & ~(size_t)255;
    return p;
  };

  int*    cnt      = (int*)alloc((size_t)N * 4);
  int*    fillc    = (int*)alloc((size_t)N * 4);
  int*    rowstart = (int*)alloc((size_t)N * 4);
  float*  dinv     = (float*)alloc((size_t)N * 4);
  const int nb     = (N + SCAN_B - 1) / SCAN_B;
  int*    bsum     = (int*)alloc((size_t)nb * 4);
  float2* ew       = (float2*)alloc(((size_t)E + N) * 8);
  float*  h        = (float*)alloc((size_t)N * F1 * 4);
  float*  h1       = (float*)alloc((size_t)N * F1 * 4);
  float*  h2       = h;  // reuse
  unsigned short* W1h = (unsigned short*)alloc((size_t)F0 * F1 * 2);
  unsigned short* W1l = (unsigned short*)alloc((size_t)F0 * F1 * 2);
  unsigned short* W2h = (unsigned short*)alloc((size_t)F1 * F2 * 2);
  unsigned short* W2l = (unsigned short*)alloc((size_t)F1 * F2 * 2);

  zero2_kernel<<<(N + 255) / 256, 256, 0, stream>>>(cnt, fillc, N);
  count_kernel<<<(E + 255) / 256, 256, 0, stream>>>(ei, cnt, E);
  dinv_kernel<<<(N + 255) / 256, 256, 0, stream>>>(cnt, dinv, N);
  scan1_kernel<<<nb, SCAN_B, 0, stream>>>(cnt, rowstart, bsum, N);
  scan2_kernel<<<1, SCAN_B, 0, stream>>>(bsum, nb);
  scan3_kernel<<<(N + 255) / 256, 256, 0, stream>>>(rowstart, bsum, N);
  fill_kernel<<<(E + 255) / 256, 256, 0, stream>>>(ei, fillc, rowstart, dinv, ew, E);
  selfedge_kernel<<<(N + 255) / 256, 256, 0, stream>>>(rowstart, cnt, dinv, ew, N);
  wsplit_kernel<<<(F0 * F1 + 255) / 256, 256, 0, stream>>>(W1, W1h, W1l, F0, F1);
  wsplit_kernel<<<(F1 * F2 + 255) / 256, 256, 0, stream>>>(W2, W2h, W2l, F1, F2);

  // layer 1: h = x@W1 ; h1 = relu(agg(h) + b1)
  gemm_mfma_kernel<128, 128><<<(N + 127) / 128, 256, 0, stream>>>(x, W1h, W1l, h, N, F0);
  {
    const long blocks = ((long)N * 64 + 255) / 256;
    agg_kernel<128><<<(int)blocks, 256, 0, stream>>>(h, rowstart, cnt, ew, b1, h1, N);
  }

  // layer 2: h2 = h1@W2 ; out = relu(agg(h2) + b2)
  gemm_mfma_kernel<128, 64><<<(N + 127) / 128, 256, 0, stream>>>(h1, W2h, W2l, h2, N, F1);
  {
    const long blocks = ((long)N * 64 + 255) / 256;
    agg_kernel<64><<<(int)blocks, 256, 0, stream>>>(h2, rowstart, cnt, ew, b2, out, N);
  }
}